// Round 19
// baseline (530.873 us; speedup 1.0000x reference)
//
#include <hip/hip_runtime.h>

// ATTNRNNAgent: B=4096, N=64, E=128, A=32, nh=8, e=32, HID=256, ATT=256, N_ACT=32
// R19 = R18 + k4 FUSED INTO k3: jb-epilogue also writes h (bf16) to h_s (64KB LDS,
//       wave-private rows); after the jb loop each wave runs the 32-col output GEMM for
//       its 16 rows (A from h_s, B = out_w frag-major from L2) and writes q_out.
//       Deletes k4's 134MB hout re-read + launch. k0 packs owF frag-major.
// k1_fused: R18 verbatim (single-pass, 116KB LDS, direct-L2 frag weights, unrolled phase2).

using bfrag = __attribute__((ext_vector_type(8))) short;   // 8 bf16
using s4    = __attribute__((ext_vector_type(4))) short;   // 4 bf16
using ffrag = __attribute__((ext_vector_type(4))) float;   // 4 f32 acc

#define MFMA(a,b,c) __builtin_amdgcn_mfma_f32_16x16x32_bf16((a),(b),(c),0,0,0)
// XOR swizzle for row-major bf16 LDS tiles (16B granular)
#define SWZ(row,col,S,xm) ((row)*(S) + ((((col)&~7) ^ (((row)&(xm))<<3)) | ((col)&7)))

// ws layout (in shorts). A2 (att, 131072 x 256) first, then bf16 weights, then flag.
#define OFF_A2   0L
#define OFF_FC1  67108864L   // fc1F: frag-major [s*4+ks][4 ct][512] (32768)
#define OFF_QKV  67141632L   // qkvF: frag-major [(kind*4+cb)*8+ks][4 ct][512] (196608)
#define OFF_W6   67338240L   // k3 W6: [jb][6 gates][32][256] pre-swizzled (393216)
#define OFF_OW   67731456L   // owF: frag-major [ks*2+nt][512] (8192)
#define OFF_FLAG 67739648L
#define WS_NEED_BYTES 135479552L

__device__ inline unsigned short f2bf(float x){
  union { float f; unsigned u; } v; v.f = x;
  unsigned r = v.u + 0x7fffu + ((v.u >> 16) & 1u);   // RNE
  return (unsigned short)(r >> 16);
}
__device__ inline bool getmask(const void* p, long i, int byteflag){
  return byteflag ? (((const unsigned char*)p)[i] != 0)
                  : (((const int*)p)[i] != 0);
}
__device__ inline ffrag fzero(){ ffrag z; z[0]=0.f; z[1]=0.f; z[2]=0.f; z[3]=0.f; return z; }
// async global->LDS, 16B per lane; lds ptr must be wave-uniform (HW adds lane*16)
__device__ inline void gload16(const short* g, short* l){
  __builtin_amdgcn_global_load_lds((const __attribute__((address_space(1))) void*)g,
                                   (__attribute__((address_space(3))) void*)l, 16, 0, 0);
}
__device__ inline bfrag packbf(const float* p){
  float4 f0 = *(const float4*)p; float4 f1 = *(const float4*)(p+4);
  bfrag v;
  v[0]=(short)f2bf(f0.x); v[1]=(short)f2bf(f0.y); v[2]=(short)f2bf(f0.z); v[3]=(short)f2bf(f0.w);
  v[4]=(short)f2bf(f1.x); v[5]=(short)f2bf(f1.y); v[6]=(short)f2bf(f1.z); v[7]=(short)f2bf(f1.w);
  return v;
}

// ---------------- K0: weights -> bf16 (frag-major fc1F/qkvF/owF, pre-swizzled W6), mask -----
__global__ void k0_prep(const float* __restrict__ fc1, const float* __restrict__ qw,
    const float* __restrict__ kw, const float* __restrict__ vw, const float* __restrict__ wih,
    const float* __restrict__ whh, const float* __restrict__ ow,
    const void* __restrict__ obsm, short* __restrict__ ws){
  long tid = (long)blockIdx.x*blockDim.x + threadIdx.x;
  long n = (long)gridDim.x*blockDim.x;
  if (tid == 0){
    const int* mi = (const int*)obsm;
    int f = 0;
    for (int i=0;i<256;i++){ if ((unsigned)mi[i] > 1u){ f = 1; break; } }
    ((int*)(ws + OFF_FLAG))[0] = f;
  }
  // fc1F: frag-major. src (outcol R 0..255, k C 0..127).
  for (long i=tid; i<32768; i+=n){
    int R = (int)(i>>7), C = (int)(i&127);
    int s = R>>6, colr = R&63, ct = colr>>4, ll = colr&15;
    int ks = C>>5, rem = C&31, lh = rem>>3, j = rem&7;
    long dst = ((long)((s*4+ks)*4+ct))*512 + (lh*16+ll)*8 + j;
    ws[OFF_FC1 + dst] = (short)f2bf(fc1[i]);
  }
  // qkvF: frag-major. src (outcol R 0..255, k C 0..255) per kind.
  for (long i=tid; i<65536; i+=n){
    int R = (int)(i>>8), C = (int)(i&255);
    int cb = R>>6, colr = R&63, ct = colr>>4, ll = colr&15;
    int ks = C>>5, rem = C&31, lh = rem>>3, j = rem&7;
    long fo = ((long)ks)*4 + ct;
    long dst = (long)(lh*16+ll)*8 + j + fo*512;
    ws[OFF_QKV + ((long)(0*4+cb))*16384 + dst] = (short)f2bf(qw[i]);
    ws[OFF_QKV + ((long)(1*4+cb))*16384 + dst] = (short)f2bf(kw[i]);
    ws[OFF_QKV + ((long)(2*4+cb))*16384 + dst] = (short)f2bf(vw[i]);
  }
  // k3 W6: [jb][g][row32][256], g = {wih.r,z,n, whh.r,z,n}; col pre-XOR'd
  for (long i=tid; i<196608; i+=n){
    int gate = (int)(i >> 16);
    int grow = (int)((i >> 8) & 255);
    int c = (int)(i & 255);
    int jb = grow >> 5, row = grow & 31;
    int cs = c ^ ((row&7)<<3);
    ws[OFF_W6 + ((long)((jb*6 + gate)*32 + row))*256 + cs]     = (short)f2bf(wih[i]);
    ws[OFF_W6 + ((long)((jb*6 + 3 + gate)*32 + row))*256 + cs] = (short)f2bf(whh[i]);
  }
  // owF: frag-major. src (outcol R 0..31, k C 0..255).
  for (long i=tid; i<8192; i+=n){
    int R = (int)(i>>8), C = (int)(i&255);
    int nt = R>>4, ll = R&15;
    int ks = C>>5, rem = C&31, lh = rem>>3, j = rem&7;
    long dst = ((long)(ks*2+nt))*512 + (lh*16+ll)*8 + j;
    ws[OFF_OW + dst] = (short)f2bf(ow[i]);
  }
}

// ---------------- K1: fused fc1 + QKV + attention; weights direct-from-L2 frags -----------
// LDS (shorts): x_s 0(16384; phase3: p_s 8x2048) | a_s/q_s 16384(8192) | k_s 24576(16384)
//               | vT_s 40960(16384) | m8 57344(2048)  => 116 KB
__global__ __launch_bounds__(512) void k1_fused(const float* __restrict__ inp,
    const short* __restrict__ fc1F, const float* __restrict__ fc1_b,
    const short* __restrict__ qkvF,
    const float* __restrict__ qb, const float* __restrict__ kb, const float* __restrict__ vb,
    const void* __restrict__ obsm, short* __restrict__ A2, const int* __restrict__ flagp){
  __shared__ __align__(16) short smem[59392];   // 116 KB
  short* x_s  = smem;               // phase1 out; phase3 p_s
  short* a_s  = smem + 16384;       // phase1 A
  short* q_s  = smem + 16384;       // phase2+ (aliases a_s)
  short* k_s  = smem + 24576;
  short* vT_s = smem + 40960;
  unsigned char* m8 = (unsigned char*)(smem + 57344);
  int t = threadIdx.x; int b = blockIdx.x;
  int lane = t&63, w = t>>6, lr = lane&15, ko = lane>>4;
  int mflag = *flagp;
  // ---- phase0: stage inp->a_s, mask->m8 ----
  #pragma unroll
  for (int i=0;i<2;i++){
    int c = t + i*512; int row = c>>4; int cc = (c&15)*8;
    *(bfrag*)(a_s + SWZ(row, cc, 128, 7)) = packbf(inp + ((long)b*64 + row)*128 + cc);
  }
  if (mflag){
    uchar4 mv = *(const uchar4*)((const unsigned char*)obsm + (long)b*4096 + t*4);
    m8[t*4]=mv.x; m8[t*4+1]=mv.y; m8[t*4+2]=mv.z; m8[t*4+3]=mv.w;
  } else {
    int4 mv = *(const int4*)((const int*)obsm + (long)b*4096 + t*4);
    m8[t*4]  =(unsigned char)(mv.x!=0); m8[t*4+1]=(unsigned char)(mv.y!=0);
    m8[t*4+2]=(unsigned char)(mv.z!=0); m8[t*4+3]=(unsigned char)(mv.w!=0);
  }
  __syncthreads();
  // ---- phase1: fc1, 4 segs of 64 cols; wave = (rg1=w&3: 16 rows) x (ch1=w>>2: 32 cols)
  {
    int rg1 = w&3, ch1 = w>>2;
    bfrag a1[4];
    #pragma unroll
    for (int ks=0;ks<4;ks++)
      a1[ks] = *(const bfrag*)(a_s + SWZ(rg1*16+lr, ks*32+ko*8, 128, 7));
    #pragma unroll
    for (int s=0;s<4;s++){
      ffrag acc[2]; acc[0]=fzero(); acc[1]=fzero();
      #pragma unroll
      for (int ks=0;ks<4;ks++){
        #pragma unroll
        for (int nt=0;nt<2;nt++){
          int ct = ch1*2 + nt;
          bfrag bb = *(const bfrag*)(fc1F + ((long)((s*4+ks)*4+ct))*512 + lane*8);
          acc[nt] = MFMA(a1[ks], bb, acc[nt]);
        }
      }
      #pragma unroll
      for (int nt=0;nt<2;nt++){
        int colg = s*64 + ch1*32 + nt*16 + lr;
        float bias = fc1_b[colg];
        #pragma unroll
        for (int r=0;r<4;r++){
          int row = rg1*16 + ko*4 + r;
          float v = acc[nt][r] + bias; v = v>0.f?v:0.f;
          x_s[SWZ(row, colg, 256, 7)] = (short)f2bf(v);
        }
      }
    }
  }
  __syncthreads();   // x complete
  // ---- phase2: qkv, 12 segs FULLY UNROLLED; wave = (rg=w&1: 32 rows, mt=2) x (chs: 16 cols)
  {
    int rg = w&1, chs = w>>1;
    bfrag a_r[2][8];
    #pragma unroll
    for (int mt=0;mt<2;mt++)
      #pragma unroll
      for (int kk=0;kk<8;kk++)
        a_r[mt][kk] = *(const bfrag*)(x_s + SWZ(rg*32+mt*16+lr, kk*32+ko*8, 256, 7));
    __syncthreads();   // everyone done reading x_s (dead until phase3 p_s)
    #pragma unroll
    for (int s=0; s<12; s++){
      int kind = s>>2, cb = s&3;
      bool active = !(kind==0 && rg==1);   // q has only 32 rows
      if (active){
        const short* fb = qkvF + (long)s*16384 + (long)chs*512 + lane*8;
        ffrag acc0=fzero(), acc1=fzero();
        #pragma unroll
        for (int ks=0;ks<8;ks++){
          bfrag bb = *(const bfrag*)(fb + (long)ks*2048);
          acc0 = MFMA(a_r[0][ks], bb, acc0);
          acc1 = MFMA(a_r[1][ks], bb, acc1);
        }
        int colg = cb*64 + chs*16 + lr;
        if (kind==0){
          float bias = qb[colg];
          #pragma unroll
          for (int r=0;r<4;r++){
            q_s[SWZ(ko*4+r, colg, 256, 7)]    = (short)f2bf(acc0[r] + bias);
            q_s[SWZ(16+ko*4+r, colg, 256, 7)] = (short)f2bf(acc1[r] + bias);
          }
        } else if (kind==1){
          float bias = kb[colg];
          #pragma unroll
          for (int r=0;r<4;r++){
            k_s[SWZ(rg*32+ko*4+r, colg, 256, 7)]    = (short)f2bf(acc0[r] + bias);
            k_s[SWZ(rg*32+16+ko*4+r, colg, 256, 7)] = (short)f2bf(acc1[r] + bias);
          }
        } else {
          float bias = vb[colg];
          int hh = colg>>5, e = colg&31;
          #pragma unroll
          for (int mt=0;mt<2;mt++){
            int n0 = rg*32 + mt*16 + ko*4;
            s4 pk;
            #pragma unroll
            for (int r=0;r<4;r++){
              float v = (mt?acc1[r]:acc0[r]) + bias; v = v>0.f?v:0.f;
              pk[r] = (short)f2bf(v);
            }
            *(s4*)(vT_s + hh*2048 + SWZ(e, n0, 64, 7)) = pk;   // 4 n contiguous 8B
          }
        }
      }
    }
  }
  __syncthreads();   // q/k/vT complete
  // ---- phase3: attention, wave w = head h (p_s aliases x_s) ----
  {
    const int h = w;
    short* p_s = x_s + h*2048;
    bfrag a_q[2];
    #pragma unroll
    for (int mt=0; mt<2; mt++)
      a_q[mt] = *(const bfrag*)(q_s + SWZ(mt*16+lr, h*32+ko*8, 256, 7));
    bfrag b_k[4];
    #pragma unroll
    for (int nt=0; nt<4; nt++)
      b_k[nt] = *(const bfrag*)(k_s + SWZ(nt*16+lr, h*32+ko*8, 256, 7));
    ffrag sc[2][4];
    #pragma unroll
    for (int mt=0; mt<2; mt++)
      #pragma unroll
      for (int nt=0; nt<4; nt++) sc[mt][nt] = MFMA(a_q[mt], b_k[nt], fzero());
    const float scale = 0.17677669529663687f;   // 1/sqrt(32)
    float rsi[2][4];
    #pragma unroll
    for (int mt=0; mt<2; mt++){
      #pragma unroll
      for (int r=0; r<4; r++){
        int arow = mt*16 + ko*4 + r;
        float sv[4]; int mk[4];
        #pragma unroll
        for (int nt=0; nt<4; nt++){
          mk[nt] = m8[arow*64 + nt*16 + lr];
          sv[nt] = sc[mt][nt][r] * scale;
        }
        float mx = -3.0e38f;
        #pragma unroll
        for (int nt=0; nt<4; nt++) if (!mk[nt]) mx = fmaxf(mx, sv[nt]);
        for (int d=1; d<16; d<<=1) mx = fmaxf(mx, __shfl_xor(mx, d));
        float sum = 0.f;
        #pragma unroll
        for (int nt=0; nt<4; nt++){
          float p = mk[nt] ? 0.f : __expf(sv[nt]-mx);
          sv[nt] = p; sum += p;
        }
        for (int d=1; d<16; d<<=1) sum += __shfl_xor(sum, d);
        rsi[mt][r] = sum > 0.f ? 1.f/sum : 0.f;   // all-masked row -> 0
        #pragma unroll
        for (int nt=0; nt<4; nt++)
          p_s[SWZ(arow, nt*16+lr, 64, 7)] = (short)f2bf(sv[nt]);
      }
    }
    ffrag o[2][2];
    #pragma unroll
    for (int mt=0;mt<2;mt++)
      #pragma unroll
      for (int nt=0;nt<2;nt++) o[mt][nt]=fzero();
    #pragma unroll
    for (int kk=0; kk<2; kk++){
      int kc = kk*32 + ko*8;
      bfrag pa0 = *(const bfrag*)(p_s + SWZ(lr,    kc, 64, 7));
      bfrag pa1 = *(const bfrag*)(p_s + SWZ(16+lr, kc, 64, 7));
      bfrag bv0 = *(const bfrag*)(vT_s + h*2048 + SWZ(lr,    kc, 64, 7));
      bfrag bv1 = *(const bfrag*)(vT_s + h*2048 + SWZ(16+lr, kc, 64, 7));
      o[0][0]=MFMA(pa0,bv0,o[0][0]); o[0][1]=MFMA(pa0,bv1,o[0][1]);
      o[1][0]=MFMA(pa1,bv0,o[1][0]); o[1][1]=MFMA(pa1,bv1,o[1][1]);
    }
    #pragma unroll
    for (int mt=0; mt<2; mt++)
      #pragma unroll
      for (int nt=0; nt<2; nt++)
        #pragma unroll
        for (int r=0; r<4; r++){
          int a = mt*16 + ko*4 + r;
          A2[((long)b*32 + a)*256 + h*32 + nt*16 + lr] = (short)f2bf(o[mt][nt][r]*rsi[mt][r]);
        }
  }
}

// ---------------- K3: GRU + fused output head ----------------
// A = [att (A2 bf16) | h0 (fp32, packed in-reg)]; mt=1, jb-in-block, 2x32KB ping-pong.
// jb epilogue also deposits h (bf16, masked) into h_s (wave-private rows); after the jb
// loop each wave computes q_out for its 16 rows (A from h_s, B = owF from L2, 16 MFMA).
__global__ __launch_bounds__(512) void k3_gru(const short* __restrict__ A2,
    const float* __restrict__ h0f, const short* __restrict__ w6,
    const float* __restrict__ b_ih, const float* __restrict__ b_hh,
    const short* __restrict__ owF, const float* __restrict__ out_b,
    const void* __restrict__ scen, float* __restrict__ hout, float* __restrict__ qout,
    const int* __restrict__ flagp){
  __shared__ __align__(16) short w_s[2][16384];   // 2 x 32 KB
  __shared__ __align__(16) short h_s[32768];      // 128 x 256 bf16 (SWZ), 64 KB
  int t = threadIdx.x, bid = blockIdx.x;
  long R0 = (long)bid * 128;
  int mflag = *flagp;
  int lane = t&63, w = t>>6, lr = lane&15, ko = lane>>4;
  long rowbase = R0 + (long)w*16;
  auto STAGE = [&](int ph){
    const short* src = w6 + (long)ph*16384;
    short* dst = w_s[ph&1];
    #pragma unroll
    for (int i=0;i<4;i++)
      gload16(src + (long)(i*512 + t)*8, dst + (i*512 + (t & ~63))*8);
  };
  STAGE(0);
  const short* Ab = A2 + (rowbase + lr)*256 + ko*8;
  const float* Hb = h0f + (rowbase + lr)*256 + ko*8;
  bfrag A[16];
  #pragma unroll
  for (int ks=0; ks<8; ks++)
    A[ks] = *(const bfrag*)(Ab + ks*32);
  #pragma unroll
  for (int ks=0; ks<8; ks++)
    A[8+ks] = packbf(Hb + ks*32);
  __syncthreads();
  for (int jb=0; jb<8; jb++){
    ffrag aR[2], aZ[2], aI[2], aN[2];
    #pragma unroll
    for (int nt=0;nt<2;nt++){ aR[nt]=fzero(); aZ[nt]=fzero(); aI[nt]=fzero(); aN[nt]=fzero(); }
    #pragma unroll
    for (int p=0; p<3; p++){
      int ph = jb*3 + p;
      if (ph < 23) STAGE(ph+1);
      const short* wc = w_s[ph&1];
      #pragma unroll
      for (int ks=0; ks<8; ks++){
        int kc = ks*32 + ko*8;
        #pragma unroll
        for (int nt=0; nt<2; nt++){
          bfrag b0 = *(const bfrag*)(wc + SWZ(nt*16+lr, kc, 256, 7));
          bfrag b1 = *(const bfrag*)(wc + 8192 + SWZ(nt*16+lr, kc, 256, 7));
          if (p == 0){
            aR[nt] = MFMA(A[ks], b0, aR[nt]);
            aZ[nt] = MFMA(A[ks], b1, aZ[nt]);
          } else if (p == 1){
            aI[nt] = MFMA(A[ks], b0, aI[nt]);
            aR[nt] = MFMA(A[8+ks], b1, aR[nt]);
          } else {
            aZ[nt] = MFMA(A[8+ks], b0, aZ[nt]);
            aN[nt] = MFMA(A[8+ks], b1, aN[nt]);
          }
        }
      }
      if (p == 2){
        #pragma unroll
        for (int nt=0; nt<2; nt++){
          int j = jb*32 + nt*16 + lr;
          float bir = b_ih[j],     bhr = b_hh[j];
          float biz = b_ih[256+j], bhz = b_hh[256+j];
          float bin = b_ih[512+j], bhn = b_hh[512+j];
          #pragma unroll
          for (int rr=0; rr<4; rr++){
            int rowl = w*16 + ko*4 + rr;
            long row = R0 + rowl;
            float rg = 1.f/(1.f + __expf(-(aR[nt][rr] + bir + bhr)));
            float zg = 1.f/(1.f + __expf(-(aZ[nt][rr] + biz + bhz)));
            float ag = aI[nt][rr] + bin + rg*(aN[nt][rr] + bhn);
            float ng = 2.f/(1.f + __expf(-2.f*ag)) - 1.f;   // tanh
            float h0v = h0f[row*256 + j];
            float hv = (1.f - zg)*ng + zg*h0v;
            if (getmask(scen, row, mflag)) hv = 0.f;
            hout[row*256 + j] = hv;
            h_s[SWZ(rowl, j, 256, 7)] = (short)f2bf(hv);
          }
        }
      }
      __syncthreads();
    }
  }
  // ---- fused output head: q_out rows rowbase..rowbase+15 (wave-private h_s rows) ----
  {
    bfrag ah[8];
    #pragma unroll
    for (int ks=0; ks<8; ks++)
      ah[ks] = *(const bfrag*)(h_s + SWZ(w*16+lr, ks*32+ko*8, 256, 7));
    ffrag oq[2]; oq[0]=fzero(); oq[1]=fzero();
    #pragma unroll
    for (int ks=0; ks<8; ks++){
      #pragma unroll
      for (int nt=0; nt<2; nt++){
        bfrag bb = *(const bfrag*)(owF + ((long)(ks*2+nt))*512 + lane*8);
        oq[nt] = MFMA(ah[ks], bb, oq[nt]);
      }
    }
    #pragma unroll
    for (int nt=0; nt<2; nt++){
      int col = nt*16 + lr;
      float ob = out_b[col];
      #pragma unroll
      for (int r=0;r<4;r++){
        long row = rowbase + ko*4 + r;
        float qv = oq[nt][r] + ob;
        if (getmask(scen, row, mflag)) qv = 0.f;
        qout[row*32 + col] = qv;
      }
    }
  }
}

extern "C" void kernel_launch(void* const* d_in, const int* in_sizes, int n_in,
                              void* d_out, int out_size, void* d_ws, size_t ws_size,
                              hipStream_t stream){
  const float* inputs = (const float*)d_in[0];
  const float* hidden = (const float*)d_in[1];
  const float* fc1_w  = (const float*)d_in[2];
  const float* fc1_b  = (const float*)d_in[3];
  const float* q_w    = (const float*)d_in[4];
  const float* q_b    = (const float*)d_in[5];
  const float* k_w    = (const float*)d_in[6];
  const float* k_b    = (const float*)d_in[7];
  const float* v_w    = (const float*)d_in[8];
  const float* v_b    = (const float*)d_in[9];
  const float* w_ih   = (const float*)d_in[10];
  const float* w_hh   = (const float*)d_in[11];
  const float* b_ih   = (const float*)d_in[12];
  const float* b_hh   = (const float*)d_in[13];
  const float* out_w  = (const float*)d_in[14];
  const float* out_b  = (const float*)d_in[15];
  const void* obsm    = d_in[16];
  const void* scen    = d_in[17];
  (void)in_sizes; (void)n_in; (void)out_size;
  if ((long)ws_size < WS_NEED_BYTES) return;
  short* ws = (short*)d_ws;
  const int* flagp = (const int*)(ws + OFF_FLAG);
  float* qout = (float*)d_out;
  float* hout = qout + 4194304;
  short* A2  = ws + OFF_A2;

  hipLaunchKernelGGL(k0_prep, dim3(512), dim3(256), 0, stream,
      fc1_w, q_w, k_w, v_w, w_ih, w_hh, out_w, obsm, ws);
  hipLaunchKernelGGL(k1_fused, dim3(4096), dim3(512), 0, stream,
      inputs, ws + OFF_FC1, fc1_b, ws + OFF_QKV, q_b, k_b, v_b, obsm, A2, flagp);
  hipLaunchKernelGGL(k3_gru, dim3(1024), dim3(512), 0, stream,
      A2, hidden, ws + OFF_W6, b_ih, b_hh, ws + OFF_OW, out_b, scen, hout, qout, flagp);
}

// Round 20
// 528.950 us; speedup vs baseline: 1.0036x; 1.0036x over previous
//
#include <hip/hip_runtime.h>

// ATTNRNNAgent: B=4096, N=64, E=128, A=32, nh=8, e=32, HID=256, ATT=256, N_ACT=32
// FINAL (R18 config, best measured 530us from 988us baseline):
//  k0: weights -> bf16, frag-major fc1F/qkvF/owF-style packs + pre-swizzled W6, mask-dtype detect
//  k1_fused: per-batch block; fc1 -> x_s -> qkv -> LDS -> per-head attention -> att to A2.
//            Weights read DIRECT from L2 as frag-major 1KB lines; 4 barriers; phase2 unrolled.
//  k3_gru:   A=[att|h0]; A-panel register-resident (mt=1, 64 VGPR fits the 128-VGPR
//            allocator cap); jb-in-block; 2x32KB ping-pong via global_load_lds of
//            pre-swizzled W6 (rule #21: linear fill == SWZ read layout).
//  k4_out:   output head from hout.
// Locked lessons: manual-RNE f2bf only (cvt_pk truncates -> 3.6e-2 fail, R16);
//  >128 VGPR unreachable (R5-R7); LDS-halving never bought occupancy (R11/R17).

using bfrag = __attribute__((ext_vector_type(8))) short;   // 8 bf16
using s4    = __attribute__((ext_vector_type(4))) short;   // 4 bf16
using ffrag = __attribute__((ext_vector_type(4))) float;   // 4 f32 acc

#define MFMA(a,b,c) __builtin_amdgcn_mfma_f32_16x16x32_bf16((a),(b),(c),0,0,0)
// XOR swizzle for row-major bf16 LDS tiles (16B granular)
#define SWZ(row,col,S,xm) ((row)*(S) + ((((col)&~7) ^ (((row)&(xm))<<3)) | ((col)&7)))

// ws layout (in shorts). A2 (att, 131072 x 256) first, then bf16 weights, then flag.
#define OFF_A2   0L
#define OFF_FC1  67108864L   // fc1F: frag-major [s*4+ks][4 ct][512] (32768)
#define OFF_QKV  67141632L   // qkvF: frag-major [(kind*4+cb)*8+ks][4 ct][512] (196608)
#define OFF_W6   67338240L   // k3 W6: [jb][6 gates][32][256] pre-swizzled (393216)
#define OFF_OW   67731456L
#define OFF_FLAG 67739648L
#define WS_NEED_BYTES 135479552L

__device__ inline unsigned short f2bf(float x){
  union { float f; unsigned u; } v; v.f = x;
  unsigned r = v.u + 0x7fffu + ((v.u >> 16) & 1u);   // RNE
  return (unsigned short)(r >> 16);
}
__device__ inline bool getmask(const void* p, long i, int byteflag){
  return byteflag ? (((const unsigned char*)p)[i] != 0)
                  : (((const int*)p)[i] != 0);
}
__device__ inline ffrag fzero(){ ffrag z; z[0]=0.f; z[1]=0.f; z[2]=0.f; z[3]=0.f; return z; }
// async global->LDS, 16B per lane; lds ptr must be wave-uniform (HW adds lane*16)
__device__ inline void gload16(const short* g, short* l){
  __builtin_amdgcn_global_load_lds((const __attribute__((address_space(1))) void*)g,
                                   (__attribute__((address_space(3))) void*)l, 16, 0, 0);
}
__device__ inline bfrag packbf(const float* p){
  float4 f0 = *(const float4*)p; float4 f1 = *(const float4*)(p+4);
  bfrag v;
  v[0]=(short)f2bf(f0.x); v[1]=(short)f2bf(f0.y); v[2]=(short)f2bf(f0.z); v[3]=(short)f2bf(f0.w);
  v[4]=(short)f2bf(f1.x); v[5]=(short)f2bf(f1.y); v[6]=(short)f2bf(f1.z); v[7]=(short)f2bf(f1.w);
  return v;
}

// ---------------- K0: weights -> bf16 (frag-major fc1F/qkvF, pre-swizzled W6), mask ----------
__global__ void k0_prep(const float* __restrict__ fc1, const float* __restrict__ qw,
    const float* __restrict__ kw, const float* __restrict__ vw, const float* __restrict__ wih,
    const float* __restrict__ whh, const float* __restrict__ ow,
    const void* __restrict__ obsm, short* __restrict__ ws){
  long tid = (long)blockIdx.x*blockDim.x + threadIdx.x;
  long n = (long)gridDim.x*blockDim.x;
  if (tid == 0){
    const int* mi = (const int*)obsm;
    int f = 0;
    for (int i=0;i<256;i++){ if ((unsigned)mi[i] > 1u){ f = 1; break; } }
    ((int*)(ws + OFF_FLAG))[0] = f;
  }
  // fc1F: frag-major. src (outcol R 0..255, k C 0..127).
  for (long i=tid; i<32768; i+=n){
    int R = (int)(i>>7), C = (int)(i&127);
    int s = R>>6, colr = R&63, ct = colr>>4, ll = colr&15;
    int ks = C>>5, rem = C&31, lh = rem>>3, j = rem&7;
    long dst = ((long)((s*4+ks)*4+ct))*512 + (lh*16+ll)*8 + j;
    ws[OFF_FC1 + dst] = (short)f2bf(fc1[i]);
  }
  // qkvF: frag-major. src (outcol R 0..255, k C 0..255) per kind.
  for (long i=tid; i<65536; i+=n){
    int R = (int)(i>>8), C = (int)(i&255);
    int cb = R>>6, colr = R&63, ct = colr>>4, ll = colr&15;
    int ks = C>>5, rem = C&31, lh = rem>>3, j = rem&7;
    long fo = ((long)ks)*4 + ct;
    long dst = (long)(lh*16+ll)*8 + j + fo*512;
    ws[OFF_QKV + ((long)(0*4+cb))*16384 + dst] = (short)f2bf(qw[i]);
    ws[OFF_QKV + ((long)(1*4+cb))*16384 + dst] = (short)f2bf(kw[i]);
    ws[OFF_QKV + ((long)(2*4+cb))*16384 + dst] = (short)f2bf(vw[i]);
  }
  // k3 W6: [jb][g][row32][256], g = {wih.r,z,n, whh.r,z,n}; col pre-XOR'd
  for (long i=tid; i<196608; i+=n){
    int gate = (int)(i >> 16);
    int grow = (int)((i >> 8) & 255);
    int c = (int)(i & 255);
    int jb = grow >> 5, row = grow & 31;
    int cs = c ^ ((row&7)<<3);
    ws[OFF_W6 + ((long)((jb*6 + gate)*32 + row))*256 + cs]     = (short)f2bf(wih[i]);
    ws[OFF_W6 + ((long)((jb*6 + 3 + gate)*32 + row))*256 + cs] = (short)f2bf(whh[i]);
  }
  for (long i=tid; i<8192; i+=n) ws[OFF_OW+i] = (short)f2bf(ow[i]);
}

// ---------------- K1: fused fc1 + QKV + attention; weights direct-from-L2 frags -----------
// LDS (shorts): x_s 0(16384; phase3: p_s 8x2048) | a_s/q_s 16384(8192) | k_s 24576(16384)
//               | vT_s 40960(16384) | m8 57344(2048)  => 116 KB
__global__ __launch_bounds__(512) void k1_fused(const float* __restrict__ inp,
    const short* __restrict__ fc1F, const float* __restrict__ fc1_b,
    const short* __restrict__ qkvF,
    const float* __restrict__ qb, const float* __restrict__ kb, const float* __restrict__ vb,
    const void* __restrict__ obsm, short* __restrict__ A2, const int* __restrict__ flagp){
  __shared__ __align__(16) short smem[59392];   // 116 KB
  short* x_s  = smem;               // phase1 out; phase3 p_s
  short* a_s  = smem + 16384;       // phase1 A
  short* q_s  = smem + 16384;       // phase2+ (aliases a_s)
  short* k_s  = smem + 24576;
  short* vT_s = smem + 40960;
  unsigned char* m8 = (unsigned char*)(smem + 57344);
  int t = threadIdx.x; int b = blockIdx.x;
  int lane = t&63, w = t>>6, lr = lane&15, ko = lane>>4;
  int mflag = *flagp;
  // ---- phase0: stage inp->a_s, mask->m8 ----
  #pragma unroll
  for (int i=0;i<2;i++){
    int c = t + i*512; int row = c>>4; int cc = (c&15)*8;
    *(bfrag*)(a_s + SWZ(row, cc, 128, 7)) = packbf(inp + ((long)b*64 + row)*128 + cc);
  }
  if (mflag){
    uchar4 mv = *(const uchar4*)((const unsigned char*)obsm + (long)b*4096 + t*4);
    m8[t*4]=mv.x; m8[t*4+1]=mv.y; m8[t*4+2]=mv.z; m8[t*4+3]=mv.w;
  } else {
    int4 mv = *(const int4*)((const int*)obsm + (long)b*4096 + t*4);
    m8[t*4]  =(unsigned char)(mv.x!=0); m8[t*4+1]=(unsigned char)(mv.y!=0);
    m8[t*4+2]=(unsigned char)(mv.z!=0); m8[t*4+3]=(unsigned char)(mv.w!=0);
  }
  __syncthreads();
  // ---- phase1: fc1, 4 segs of 64 cols; wave = (rg1=w&3: 16 rows) x (ch1=w>>2: 32 cols)
  {
    int rg1 = w&3, ch1 = w>>2;
    bfrag a1[4];
    #pragma unroll
    for (int ks=0;ks<4;ks++)
      a1[ks] = *(const bfrag*)(a_s + SWZ(rg1*16+lr, ks*32+ko*8, 128, 7));
    #pragma unroll
    for (int s=0;s<4;s++){
      ffrag acc[2]; acc[0]=fzero(); acc[1]=fzero();
      #pragma unroll
      for (int ks=0;ks<4;ks++){
        #pragma unroll
        for (int nt=0;nt<2;nt++){
          int ct = ch1*2 + nt;
          bfrag bb = *(const bfrag*)(fc1F + ((long)((s*4+ks)*4+ct))*512 + lane*8);
          acc[nt] = MFMA(a1[ks], bb, acc[nt]);
        }
      }
      #pragma unroll
      for (int nt=0;nt<2;nt++){
        int colg = s*64 + ch1*32 + nt*16 + lr;
        float bias = fc1_b[colg];
        #pragma unroll
        for (int r=0;r<4;r++){
          int row = rg1*16 + ko*4 + r;
          float v = acc[nt][r] + bias; v = v>0.f?v:0.f;
          x_s[SWZ(row, colg, 256, 7)] = (short)f2bf(v);
        }
      }
    }
  }
  __syncthreads();   // x complete
  // ---- phase2: qkv, 12 segs FULLY UNROLLED; wave = (rg=w&1: 32 rows, mt=2) x (chs: 16 cols)
  //      B direct from qkvF (1KB frags). Wave-private writes, no barriers inside.
  {
    int rg = w&1, chs = w>>1;
    bfrag a_r[2][8];
    #pragma unroll
    for (int mt=0;mt<2;mt++)
      #pragma unroll
      for (int kk=0;kk<8;kk++)
        a_r[mt][kk] = *(const bfrag*)(x_s + SWZ(rg*32+mt*16+lr, kk*32+ko*8, 256, 7));
    __syncthreads();   // everyone done reading x_s (dead until phase3 p_s)
    #pragma unroll
    for (int s=0; s<12; s++){
      int kind = s>>2, cb = s&3;
      bool active = !(kind==0 && rg==1);   // q has only 32 rows
      if (active){
        const short* fb = qkvF + (long)s*16384 + (long)chs*512 + lane*8;
        ffrag acc0=fzero(), acc1=fzero();
        #pragma unroll
        for (int ks=0;ks<8;ks++){
          bfrag bb = *(const bfrag*)(fb + (long)ks*2048);
          acc0 = MFMA(a_r[0][ks], bb, acc0);
          acc1 = MFMA(a_r[1][ks], bb, acc1);
        }
        int colg = cb*64 + chs*16 + lr;
        if (kind==0){
          float bias = qb[colg];
          #pragma unroll
          for (int r=0;r<4;r++){
            q_s[SWZ(ko*4+r, colg, 256, 7)]    = (short)f2bf(acc0[r] + bias);
            q_s[SWZ(16+ko*4+r, colg, 256, 7)] = (short)f2bf(acc1[r] + bias);
          }
        } else if (kind==1){
          float bias = kb[colg];
          #pragma unroll
          for (int r=0;r<4;r++){
            k_s[SWZ(rg*32+ko*4+r, colg, 256, 7)]    = (short)f2bf(acc0[r] + bias);
            k_s[SWZ(rg*32+16+ko*4+r, colg, 256, 7)] = (short)f2bf(acc1[r] + bias);
          }
        } else {
          float bias = vb[colg];
          int hh = colg>>5, e = colg&31;
          #pragma unroll
          for (int mt=0;mt<2;mt++){
            int n0 = rg*32 + mt*16 + ko*4;
            s4 pk;
            #pragma unroll
            for (int r=0;r<4;r++){
              float v = (mt?acc1[r]:acc0[r]) + bias; v = v>0.f?v:0.f;
              pk[r] = (short)f2bf(v);
            }
            *(s4*)(vT_s + hh*2048 + SWZ(e, n0, 64, 7)) = pk;   // 4 n contiguous 8B
          }
        }
      }
    }
  }
  __syncthreads();   // q/k/vT complete
  // ---- phase3: attention, wave w = head h (p_s aliases x_s) ----
  {
    const int h = w;
    short* p_s = x_s + h*2048;
    bfrag a_q[2];
    #pragma unroll
    for (int mt=0; mt<2; mt++)
      a_q[mt] = *(const bfrag*)(q_s + SWZ(mt*16+lr, h*32+ko*8, 256, 7));
    bfrag b_k[4];
    #pragma unroll
    for (int nt=0; nt<4; nt++)
      b_k[nt] = *(const bfrag*)(k_s + SWZ(nt*16+lr, h*32+ko*8, 256, 7));
    ffrag sc[2][4];
    #pragma unroll
    for (int mt=0; mt<2; mt++)
      #pragma unroll
      for (int nt=0; nt<4; nt++) sc[mt][nt] = MFMA(a_q[mt], b_k[nt], fzero());
    const float scale = 0.17677669529663687f;   // 1/sqrt(32)
    float rsi[2][4];
    #pragma unroll
    for (int mt=0; mt<2; mt++){
      #pragma unroll
      for (int r=0; r<4; r++){
        int arow = mt*16 + ko*4 + r;
        float sv[4]; int mk[4];
        #pragma unroll
        for (int nt=0; nt<4; nt++){
          mk[nt] = m8[arow*64 + nt*16 + lr];
          sv[nt] = sc[mt][nt][r] * scale;
        }
        float mx = -3.0e38f;
        #pragma unroll
        for (int nt=0; nt<4; nt++) if (!mk[nt]) mx = fmaxf(mx, sv[nt]);
        for (int d=1; d<16; d<<=1) mx = fmaxf(mx, __shfl_xor(mx, d));
        float sum = 0.f;
        #pragma unroll
        for (int nt=0; nt<4; nt++){
          float p = mk[nt] ? 0.f : __expf(sv[nt]-mx);
          sv[nt] = p; sum += p;
        }
        for (int d=1; d<16; d<<=1) sum += __shfl_xor(sum, d);
        rsi[mt][r] = sum > 0.f ? 1.f/sum : 0.f;   // all-masked row -> 0
        #pragma unroll
        for (int nt=0; nt<4; nt++)
          p_s[SWZ(arow, nt*16+lr, 64, 7)] = (short)f2bf(sv[nt]);
      }
    }
    ffrag o[2][2];
    #pragma unroll
    for (int mt=0;mt<2;mt++)
      #pragma unroll
      for (int nt=0;nt<2;nt++) o[mt][nt]=fzero();
    #pragma unroll
    for (int kk=0; kk<2; kk++){
      int kc = kk*32 + ko*8;
      bfrag pa0 = *(const bfrag*)(p_s + SWZ(lr,    kc, 64, 7));
      bfrag pa1 = *(const bfrag*)(p_s + SWZ(16+lr, kc, 64, 7));
      bfrag bv0 = *(const bfrag*)(vT_s + h*2048 + SWZ(lr,    kc, 64, 7));
      bfrag bv1 = *(const bfrag*)(vT_s + h*2048 + SWZ(16+lr, kc, 64, 7));
      o[0][0]=MFMA(pa0,bv0,o[0][0]); o[0][1]=MFMA(pa0,bv1,o[0][1]);
      o[1][0]=MFMA(pa1,bv0,o[1][0]); o[1][1]=MFMA(pa1,bv1,o[1][1]);
    }
    #pragma unroll
    for (int mt=0; mt<2; mt++)
      #pragma unroll
      for (int nt=0; nt<2; nt++)
        #pragma unroll
        for (int r=0; r<4; r++){
          int a = mt*16 + ko*4 + r;
          A2[((long)b*32 + a)*256 + h*32 + nt*16 + lr] = (short)f2bf(o[mt][nt][r]*rsi[mt][r]);
        }
  }
}

// ---------------- K3: GRU; A = [att (A2 bf16) | h0 (fp32, packed in-reg)] ----------------
__global__ __launch_bounds__(512) void k3_gru(const short* __restrict__ A2,
    const float* __restrict__ h0f, const short* __restrict__ w6,
    const float* __restrict__ b_ih, const float* __restrict__ b_hh,
    const void* __restrict__ scen, float* __restrict__ hout, const int* __restrict__ flagp){
  __shared__ __align__(16) short w_s[2][16384];   // 2 x 32 KB
  int t = threadIdx.x, bid = blockIdx.x;
  long R0 = (long)bid * 128;
  int mflag = *flagp;
  int lane = t&63, w = t>>6, lr = lane&15, ko = lane>>4;
  long rowbase = R0 + (long)w*16;
  auto STAGE = [&](int ph){
    const short* src = w6 + (long)ph*16384;
    short* dst = w_s[ph&1];
    #pragma unroll
    for (int i=0;i<4;i++)
      gload16(src + (long)(i*512 + t)*8, dst + (i*512 + (t & ~63))*8);
  };
  STAGE(0);
  const short* Ab = A2 + (rowbase + lr)*256 + ko*8;
  const float* Hb = h0f + (rowbase + lr)*256 + ko*8;
  bfrag A[16];
  #pragma unroll
  for (int ks=0; ks<8; ks++)
    A[ks] = *(const bfrag*)(Ab + ks*32);
  #pragma unroll
  for (int ks=0; ks<8; ks++)
    A[8+ks] = packbf(Hb + ks*32);
  __syncthreads();
  for (int jb=0; jb<8; jb++){
    ffrag aR[2], aZ[2], aI[2], aN[2];
    #pragma unroll
    for (int nt=0;nt<2;nt++){ aR[nt]=fzero(); aZ[nt]=fzero(); aI[nt]=fzero(); aN[nt]=fzero(); }
    #pragma unroll
    for (int p=0; p<3; p++){
      int ph = jb*3 + p;
      if (ph < 23) STAGE(ph+1);
      const short* wc = w_s[ph&1];
      #pragma unroll
      for (int ks=0; ks<8; ks++){
        int kc = ks*32 + ko*8;
        #pragma unroll
        for (int nt=0; nt<2; nt++){
          bfrag b0 = *(const bfrag*)(wc + SWZ(nt*16+lr, kc, 256, 7));
          bfrag b1 = *(const bfrag*)(wc + 8192 + SWZ(nt*16+lr, kc, 256, 7));
          if (p == 0){
            aR[nt] = MFMA(A[ks], b0, aR[nt]);
            aZ[nt] = MFMA(A[ks], b1, aZ[nt]);
          } else if (p == 1){
            aI[nt] = MFMA(A[ks], b0, aI[nt]);
            aR[nt] = MFMA(A[8+ks], b1, aR[nt]);
          } else {
            aZ[nt] = MFMA(A[8+ks], b0, aZ[nt]);
            aN[nt] = MFMA(A[8+ks], b1, aN[nt]);
          }
        }
      }
      if (p == 2){
        #pragma unroll
        for (int nt=0; nt<2; nt++){
          int j = jb*32 + nt*16 + lr;
          float bir = b_ih[j],     bhr = b_hh[j];
          float biz = b_ih[256+j], bhz = b_hh[256+j];
          float bin = b_ih[512+j], bhn = b_hh[512+j];
          #pragma unroll
          for (int rr=0; rr<4; rr++){
            long row = rowbase + ko*4 + rr;
            float rg = 1.f/(1.f + __expf(-(aR[nt][rr] + bir + bhr)));
            float zg = 1.f/(1.f + __expf(-(aZ[nt][rr] + biz + bhz)));
            float ag = aI[nt][rr] + bin + rg*(aN[nt][rr] + bhn);
            float ng = 2.f/(1.f + __expf(-2.f*ag)) - 1.f;   // tanh
            float h0v = h0f[row*256 + j];
            float hv = (1.f - zg)*ng + zg*h0v;
            if (getmask(scen, row, mflag)) hv = 0.f;
            hout[row*256 + j] = hv;
          }
        }
      }
      __syncthreads();
    }
  }
}

// ---------------- K4: q_out = h @ out_w^T + out_b (masked) ----------------
__global__ __launch_bounds__(512) void k4_out(const float* __restrict__ hout,
    const short* __restrict__ ow, const float* __restrict__ out_b,
    const void* __restrict__ scen, float* __restrict__ qout, const int* __restrict__ flagp){
  __shared__ __align__(16) short ow_s[32*256];
  int t = threadIdx.x; long R0 = (long)blockIdx.x * 256;
  int mflag = *flagp;
  for (int i=0;i<2;i++){
    int c = t + i*512; int row = c >> 5; int cc = (c & 31)*8;
    *(bfrag*)(ow_s + SWZ(row, cc, 256, 7)) = *(const bfrag*)(ow + row*256 + cc);
  }
  __syncthreads();
  int lane = t&63, w = t>>6, lr = lane&15, ko = lane>>4;
  ffrag acc[2][2];
  #pragma unroll
  for (int a=0;a<2;a++) for (int bq=0;bq<2;bq++) acc[a][bq]=fzero();
  for (int ks=0; ks<8; ks++){
    int kc = ks*32 + ko*8;
    #pragma unroll
    for (int mi=0; mi<2; mi++){
      long row = R0 + (w*2+mi)*16 + lr;
      bfrag a = packbf(hout + row*256 + kc);
      #pragma unroll
      for (int nt=0; nt<2; nt++){
        bfrag bb = *(const bfrag*)(ow_s + SWZ(nt*16+lr, kc, 256, 7));
        acc[mi][nt] = MFMA(a, bb, acc[mi][nt]);
      }
    }
  }
  #pragma unroll
  for (int mi=0;mi<2;mi++)
    #pragma unroll
    for (int nt=0;nt<2;nt++){
      int col = nt*16 + lr;
      float ob = out_b[col];
      #pragma unroll
      for (int r=0;r<4;r++){
        long row = R0 + (w*2+mi)*16 + ko*4 + r;
        float qv = acc[mi][nt][r] + ob;
        if (getmask(scen, row, mflag)) qv = 0.f;
        qout[row*32 + col] = qv;
      }
    }
}

extern "C" void kernel_launch(void* const* d_in, const int* in_sizes, int n_in,
                              void* d_out, int out_size, void* d_ws, size_t ws_size,
                              hipStream_t stream){
  const float* inputs = (const float*)d_in[0];
  const float* hidden = (const float*)d_in[1];
  const float* fc1_w  = (const float*)d_in[2];
  const float* fc1_b  = (const float*)d_in[3];
  const float* q_w    = (const float*)d_in[4];
  const float* q_b    = (const float*)d_in[5];
  const float* k_w    = (const float*)d_in[6];
  const float* k_b    = (const float*)d_in[7];
  const float* v_w    = (const float*)d_in[8];
  const float* v_b    = (const float*)d_in[9];
  const float* w_ih   = (const float*)d_in[10];
  const float* w_hh   = (const float*)d_in[11];
  const float* b_ih   = (const float*)d_in[12];
  const float* b_hh   = (const float*)d_in[13];
  const float* out_w  = (const float*)d_in[14];
  const float* out_b  = (const float*)d_in[15];
  const void* obsm    = d_in[16];
  const void* scen    = d_in[17];
  (void)in_sizes; (void)n_in; (void)out_size;
  if ((long)ws_size < WS_NEED_BYTES) return;
  short* ws = (short*)d_ws;
  const int* flagp = (const int*)(ws + OFF_FLAG);
  float* qout = (float*)d_out;
  float* hout = qout + 4194304;
  short* A2  = ws + OFF_A2;

  hipLaunchKernelGGL(k0_prep, dim3(512), dim3(256), 0, stream,
      fc1_w, q_w, k_w, v_w, w_ih, w_hh, out_w, obsm, ws);
  hipLaunchKernelGGL(k1_fused, dim3(4096), dim3(512), 0, stream,
      inputs, ws + OFF_FC1, fc1_b, ws + OFF_QKV, q_b, k_b, v_b, obsm, A2, flagp);
  hipLaunchKernelGGL(k3_gru, dim3(1024), dim3(512), 0, stream,
      A2, hidden, ws + OFF_W6, b_ih, b_hh, scen, hout, flagp);
  hipLaunchKernelGGL(k4_out, dim3(512), dim3(512), 0, stream,
      hout, ws + OFF_OW, out_b, scen, qout, flagp);
}